// Round 2
// baseline (298.329 us; speedup 1.0000x reference)
//
#include <hip/hip_runtime.h>

#define DEV __device__ __forceinline__

typedef __bf16 bf16x8 __attribute__((ext_vector_type(8)));
typedef float  f32x4  __attribute__((ext_vector_type(4)));

// ---- constants ----
constexpr int B_ = 4, S_ = 2048, D_ = 1024;
constexpr int NTOK = B_ * S_;               // 8192
constexpr size_t XB_ELEMS = (size_t)NTOK * D_;        // 8,388,608
constexpr size_t WB_ELEMS = (size_t)3 * D_ * D_;      // 3,145,728
constexpr size_t OFF_XB = 0;
constexpr size_t OFF_WB = OFF_XB + XB_ELEMS * 2;      // 16,777,216
constexpr size_t OFF_QB = OFF_WB + WB_ELEMS * 2;      // 23,068,672
constexpr size_t OFF_KB = OFF_QB + XB_ELEMS * 2;
constexpr size_t OFF_VB = OFF_KB + XB_ELEMS * 2;
constexpr size_t OFF_SB = OFF_VB + XB_ELEMS * 2;      // 73,400,320 (fp32 scores, 67MB)

DEV unsigned short f2bf(float f) {            // RNE float->bf16 (bit trick, no API dependency)
  unsigned u = __float_as_uint(f);
  u += 0x7fffu + ((u >> 16) & 1u);
  return (unsigned short)(u >> 16);
}

DEV void gload16(const void* g, void* l) {    // 16B global->LDS direct (guide §5, m97)
  __builtin_amdgcn_global_load_lds(
      (const __attribute__((address_space(1))) void*)g,
      (__attribute__((address_space(3))) void*)l, 16, 0, 0);
}

// ---------------- cast fp32 -> bf16, vectorized ----------------
__global__ __launch_bounds__(256) void cast_kernel(const float* __restrict__ src,
                                                   unsigned short* __restrict__ dst, int n4) {
  int i = blockIdx.x * 256 + threadIdx.x;
  int stride = gridDim.x * 256;
  for (; i < n4; i += stride) {
    float4 v = ((const float4*)src)[i];
    ushort4 o;
    o.x = f2bf(v.x); o.y = f2bf(v.y); o.z = f2bf(v.z); o.w = f2bf(v.w);
    ((ushort4*)dst)[i] = o;
  }
}

// ---------------- shared 128x128 GEMM core (m97 structure) ----------------
// C[128,128] += A[arow0..+128, K] * B[brow0..+128, K]^T  (both row-major, K contiguous)
// 256 threads = 4 waves in 2x2; each wave 64x64 = 4x4 frags of 16x16; BK=64.
DEV void gemm_tile(const unsigned short* __restrict__ A, int lda, int arow0,
                   const unsigned short* __restrict__ B, int ldb, int brow0,
                   int ksteps, unsigned short* lsA, unsigned short* lsB,
                   f32x4 acc[4][4]) {
  const int tid  = threadIdx.x;
  const int lane = tid & 63;
  const int w    = tid >> 6;
  const int wr   = (w >> 1) * 64, wc = (w & 1) * 64;
  const int srow = tid >> 3;            // staging row 0..31 (+32 per pass)
  const int scol = (tid & 7) * 8;       // staging col (elements)
  const int fr   = lane & 15;           // fragment row/col within 16
  const int fk   = (lane >> 4) * 8;     // fragment k offset

  for (int ks = 0; ks < ksteps; ++ks) {
    const int k0 = ks * 64;
#pragma unroll
    for (int p = 0; p < 4; ++p) {       // 128x64 bf16 per operand: 4 passes x 256thr x 16B
      gload16(A + (size_t)(arow0 + p * 32 + srow) * lda + (k0 + scol), lsA + p * 2048 + tid * 8);
      gload16(B + (size_t)(brow0 + p * 32 + srow) * ldb + (k0 + scol), lsB + p * 2048 + tid * 8);
    }
    __syncthreads();                    // vmcnt(0) drain + barrier: staged data visible
#pragma unroll
    for (int kk = 0; kk < 2; ++kk) {
      bf16x8 af[4], bfv[4];
#pragma unroll
      for (int i = 0; i < 4; ++i) {
        af[i]  = *(const bf16x8*)(lsA + (size_t)(wr + i * 16 + fr) * 64 + kk * 32 + fk);
        bfv[i] = *(const bf16x8*)(lsB + (size_t)(wc + i * 16 + fr) * 64 + kk * 32 + fk);
      }
#pragma unroll
      for (int i = 0; i < 4; ++i)
#pragma unroll
        for (int j = 0; j < 4; ++j)
          acc[i][j] = __builtin_amdgcn_mfma_f32_16x16x32_bf16(af[i], bfv[j], acc[i][j], 0, 0, 0);
    }
    __syncthreads();                    // protect LDS from next-iter overwrite
  }
}

// ---------------- QKV projection: [8192,1024] x [3072,1024]^T + bias ----------------
__global__ __launch_bounds__(256) void qkv_gemm(
    const unsigned short* __restrict__ xb, const unsigned short* __restrict__ wb,
    const float* __restrict__ bq, const float* __restrict__ bk, const float* __restrict__ bv,
    unsigned short* __restrict__ qb, unsigned short* __restrict__ kb, unsigned short* __restrict__ vb) {
  __shared__ unsigned short lsA[8192], lsB[8192];
  f32x4 acc[4][4];
#pragma unroll
  for (int i = 0; i < 4; ++i)
#pragma unroll
    for (int j = 0; j < 4; ++j) { f32x4 z = {0.f, 0.f, 0.f, 0.f}; acc[i][j] = z; }
  const int mt = blockIdx.x, nt = blockIdx.y;
  gemm_tile(xb, D_, mt * 128, wb, D_, nt * 128, 16, lsA, lsB, acc);

  const int proj  = nt >> 3;
  const int ncol0 = (nt & 7) * 128;
  unsigned short* dst  = proj == 0 ? qb : (proj == 1 ? kb : vb);
  const float*    bias = proj == 0 ? bq : (proj == 1 ? bk : bv);
  const int lane = threadIdx.x & 63, w = threadIdx.x >> 6;
  const int wr = (w >> 1) * 64, wc = (w & 1) * 64;
  const int dr = (lane >> 4) * 4, dc = lane & 15;   // m89-verified C/D layout
#pragma unroll
  for (int i = 0; i < 4; ++i)
#pragma unroll
    for (int j = 0; j < 4; ++j) {
      const int c = ncol0 + wc + j * 16 + dc;
      const float bb = bias[c];
#pragma unroll
      for (int q = 0; q < 4; ++q) {
        const int r = mt * 128 + wr + i * 16 + dr + q;
        dst[(size_t)r * D_ + c] = f2bf(acc[i][j][q] + bb);
      }
    }
}

// ---------------- V transpose: [8192,1024] -> [1024,8192] ----------------
__global__ __launch_bounds__(256) void transpose_v(const unsigned short* __restrict__ vb,
                                                   unsigned short* __restrict__ vbT) {
  __shared__ unsigned short t[64][68];
  const int bt = blockIdx.x;            // token tile 0..127
  const int bo = blockIdx.y;            // o tile 0..15
  const int tid = threadIdx.x;
  const int r = tid >> 4, c4 = (tid & 15) * 4;
#pragma unroll
  for (int p = 0; p < 4; ++p) {
    ushort4 v = *(const ushort4*)(vb + (size_t)(bt * 64 + p * 16 + r) * D_ + bo * 64 + c4);
    t[p * 16 + r][c4] = v.x; t[p * 16 + r][c4 + 1] = v.y;
    t[p * 16 + r][c4 + 2] = v.z; t[p * 16 + r][c4 + 3] = v.w;
  }
  __syncthreads();
#pragma unroll
  for (int p = 0; p < 4; ++p) {
    ushort4 v;
    v.x = t[c4][p * 16 + r]; v.y = t[c4 + 1][p * 16 + r];
    v.z = t[c4 + 2][p * 16 + r]; v.w = t[c4 + 3][p * 16 + r];
    *(ushort4*)(vbT + (size_t)(bo * 64 + p * 16 + r) * NTOK + bt * 64 + c4) = v;
  }
}

// ---------------- scores = Q K^T * scale, causal lower-tri tiles only ----------------
__global__ __launch_bounds__(256) void scores_gemm(const unsigned short* __restrict__ qb,
                                                   const unsigned short* __restrict__ kb,
                                                   float* __restrict__ sbuf) {
  __shared__ unsigned short lsA[8192], lsB[8192];
  const int b = blockIdx.y;
  const int t = blockIdx.x;                       // 0..135 triangular index
  int i = (int)((sqrtf(8.f * t + 1.f) - 1.f) * 0.5f);
  while ((i + 1) * (i + 2) / 2 <= t) ++i;
  while (i * (i + 1) / 2 > t) --i;
  const int j = t - i * (i + 1) / 2;              // j <= i

  f32x4 acc[4][4];
#pragma unroll
  for (int a = 0; a < 4; ++a)
#pragma unroll
    for (int c = 0; c < 4; ++c) { f32x4 z = {0.f, 0.f, 0.f, 0.f}; acc[a][c] = z; }
  const unsigned short* Ab = qb + (size_t)b * S_ * D_;
  const unsigned short* Bb = kb + (size_t)b * S_ * D_;
  gemm_tile(Ab, D_, i * 128, Bb, D_, j * 128, 16, lsA, lsB, acc);

  float* sb = sbuf + (size_t)b * S_ * S_;
  const int lane = threadIdx.x & 63, w = threadIdx.x >> 6;
  const int wr = (w >> 1) * 64, wc = (w & 1) * 64;
  const int dr = (lane >> 4) * 4, dc = lane & 15;
  constexpr float scale = 0.03125f;               // 1/sqrt(1024)
#pragma unroll
  for (int fi = 0; fi < 4; ++fi)
#pragma unroll
    for (int fj = 0; fj < 4; ++fj) {
      const int kv = j * 128 + wc + fj * 16 + dc;
#pragma unroll
      for (int q = 0; q < 4; ++q) {
        const int qr = i * 128 + wr + fi * 16 + dr + q;
        float v = acc[fi][fj][q] * scale;
        if (kv > qr) v = -1e30f;                  // causal mask (diagonal tiles)
        sb[(size_t)qr * S_ + kv] = v;
      }
    }
}

// ---------------- row softmax, P written bf16 in-place over scores ----------------
__global__ __launch_bounds__(256) void softmax_kernel(float* __restrict__ sbuf) {
  const int b = blockIdx.y, q = blockIdx.x;
  float* row = sbuf + ((size_t)b * S_ + q) * S_;
  unsigned short* prow = (unsigned short*)row;    // bf16 row, stride S_*2 bytes within fp32 row
  const int len = q + 1;
  __shared__ float buf[S_];
  __shared__ float red[4];
  const int tid = threadIdx.x, lane = tid & 63, wv = tid >> 6;

  float m = -3e38f;
  for (int k = tid; k < len; k += 256) { float s = row[k]; buf[k] = s; m = fmaxf(m, s); }
#pragma unroll
  for (int off = 32; off >= 1; off >>= 1) m = fmaxf(m, __shfl_xor(m, off));
  if (lane == 0) red[wv] = m;
  __syncthreads();
  m = fmaxf(fmaxf(red[0], red[1]), fmaxf(red[2], red[3]));
  __syncthreads();

  float l = 0.f;
  for (int k = tid; k < len; k += 256) { float e = __expf(buf[k] - m); buf[k] = e; l += e; }
#pragma unroll
  for (int off = 32; off >= 1; off >>= 1) l += __shfl_xor(l, off);
  if (lane == 0) red[wv] = l;
  __syncthreads();
  l = red[0] + red[1] + red[2] + red[3];
  const float inv = 1.f / l;
  for (int k = tid; k < S_; k += 256) {
    float p = (k < len) ? buf[k] * inv : 0.f;     // zero-fill to tile boundary for PV
    prow[k] = f2bf(p);
  }
}

// ---------------- O = P V  (causal K bound per row tile) ----------------
// Grid: x = q-row tile DESCENDING (longest blocks dispatch first), y = out-col tile, z = batch.
__global__ __launch_bounds__(256) void pv_gemm(const unsigned short* __restrict__ pbuf,
                                               const unsigned short* __restrict__ vbT,
                                               float* __restrict__ out) {
  __shared__ unsigned short lsA[8192], lsB[8192];
  const int it = 15 - blockIdx.x;       // 15..0  q-row tile, longest first
  const int nt = blockIdx.y;            // 0..7   output-col tile
  const int b  = blockIdx.z;
  f32x4 acc[4][4];
#pragma unroll
  for (int i = 0; i < 4; ++i)
#pragma unroll
    for (int j = 0; j < 4; ++j) { f32x4 z = {0.f, 0.f, 0.f, 0.f}; acc[i][j] = z; }
  const unsigned short* Ab = pbuf + (size_t)b * S_ * (2 * S_); // P stride 4096 ushorts (in-place in fp32 rows)
  const unsigned short* Bb = vbT + (size_t)b * S_;             // column offset into [1024,8192]
  gemm_tile(Ab, 2 * S_, it * 128, Bb, NTOK, nt * 128, 2 * (it + 1), lsA, lsB, acc);

  const int lane = threadIdx.x & 63, w = threadIdx.x >> 6;
  const int wr = (w >> 1) * 64, wc = (w & 1) * 64;
  const int dr = (lane >> 4) * 4, dc = lane & 15;
#pragma unroll
  for (int fi = 0; fi < 4; ++fi)
#pragma unroll
    for (int fj = 0; fj < 4; ++fj) {
      const int c = nt * 128 + wc + fj * 16 + dc;
#pragma unroll
      for (int q = 0; q < 4; ++q) {
        const int r = it * 128 + wr + fi * 16 + dr + q;
        out[((size_t)b * S_ + r) * D_ + c] = acc[fi][fj][q];
      }
    }
}

extern "C" void kernel_launch(void* const* d_in, const int* in_sizes, int n_in,
                              void* d_out, int out_size, void* d_ws, size_t ws_size,
                              hipStream_t stream) {
  (void)in_sizes; (void)n_in; (void)out_size; (void)ws_size;
  const float* x  = (const float*)d_in[0];
  const float* wq = (const float*)d_in[1];
  const float* bq = (const float*)d_in[2];
  const float* wk = (const float*)d_in[3];
  const float* bk = (const float*)d_in[4];
  const float* wv = (const float*)d_in[5];
  const float* bv = (const float*)d_in[6];
  float* out = (float*)d_out;

  char* ws = (char*)d_ws;
  unsigned short* xb = (unsigned short*)(ws + OFF_XB);
  unsigned short* wb = (unsigned short*)(ws + OFF_WB);
  unsigned short* qb = (unsigned short*)(ws + OFF_QB);
  unsigned short* kb = (unsigned short*)(ws + OFF_KB);
  unsigned short* vb = (unsigned short*)(ws + OFF_VB);
  float*          sb = (float*)(ws + OFF_SB);
  unsigned short* vbT = xb;             // xb is dead after qkv_gemm; reuse (16.8MB)

  cast_kernel<<<2048, 256, 0, stream>>>(x,  xb, (int)(XB_ELEMS / 4));
  cast_kernel<<<1024, 256, 0, stream>>>(wq, wb,                 D_ * D_ / 4);
  cast_kernel<<<1024, 256, 0, stream>>>(wk, wb +     D_ * D_,   D_ * D_ / 4);
  cast_kernel<<<1024, 256, 0, stream>>>(wv, wb + 2 * D_ * D_,   D_ * D_ / 4);
  qkv_gemm<<<dim3(64, 24), 256, 0, stream>>>(xb, wb, bq, bk, bv, qb, kb, vb);
  transpose_v<<<dim3(128, 16), 256, 0, stream>>>(vb, vbT);
  scores_gemm<<<dim3(136, 4), 256, 0, stream>>>(qb, kb, sb);
  softmax_kernel<<<dim3(S_, 4), 256, 0, stream>>>(sb);
  pv_gemm<<<dim3(16, 8, 4), 256, 0, stream>>>((const unsigned short*)sb, vbT, out);
}

// Round 5
// 281.007 us; speedup vs baseline: 1.0616x; 1.0616x over previous
//
#include <hip/hip_runtime.h>

#define DEV __device__ __forceinline__

typedef __bf16 bf16x8 __attribute__((ext_vector_type(8)));
typedef float  f32x4  __attribute__((ext_vector_type(4)));

// ---- constants ----
constexpr int B_ = 4, S_ = 2048, D_ = 1024;
constexpr int NTOK = B_ * S_;               // 8192
constexpr size_t XB_ELEMS = (size_t)NTOK * D_;        // 8,388,608
constexpr size_t WB_ELEMS = (size_t)3 * D_ * D_;      // 3,145,728
constexpr size_t OFF_XB = 0;
constexpr size_t OFF_WB = OFF_XB + XB_ELEMS * 2;      // 16,777,216
constexpr size_t OFF_QB = OFF_WB + WB_ELEMS * 2;      // 23,068,672
constexpr size_t OFF_KB = OFF_QB + XB_ELEMS * 2;
constexpr size_t OFF_VB = OFF_KB + XB_ELEMS * 2;
constexpr size_t OFF_SB = OFF_VB + XB_ELEMS * 2;      // 73,400,320 (fp32 scores, 67MB)

DEV unsigned short f2bf(float f) {            // RNE float->bf16
  unsigned u = __float_as_uint(f);
  u += 0x7fffu + ((u >> 16) & 1u);
  return (unsigned short)(u >> 16);
}

DEV void gload16(const void* g, void* l) {    // 16B global->LDS direct
  __builtin_amdgcn_global_load_lds(
      (const __attribute__((address_space(1))) void*)g,
      (__attribute__((address_space(3))) void*)l, 16, 0, 0);
}

// ---------------- cast fp32 -> bf16, vectorized ----------------
__global__ __launch_bounds__(256) void cast_kernel(const float* __restrict__ src,
                                                   unsigned short* __restrict__ dst, int n4) {
  int i = blockIdx.x * 256 + threadIdx.x;
  int stride = gridDim.x * 256;
  for (; i < n4; i += stride) {
    float4 v = ((const float4*)src)[i];
    ushort4 o;
    o.x = f2bf(v.x); o.y = f2bf(v.y); o.z = f2bf(v.z); o.w = f2bf(v.w);
    ((ushort4*)dst)[i] = o;
  }
}

// ================= 8-phase 256x256 GEMM (T2+T3+T4+T5), QKV only =================
// 512 thr = 8 waves (2M x 4N). Per wave: 128x64 out = acc[8][4]. BK=64, 2 LDS bufs.
// LDS per buf: A[256][64] + B[256][64] bf16 (32KB+32KB); x2 bufs = 128KB.
// Swizzle: element (row,col) stored at col-byte (col*2)^((row&7)<<4)  [G4 fix for
// 128B rows]. gload_lds writes linearly -> pre-swizzle the GLOBAL source col.
// Phase schedule per K-tile T (buf = T&1), quadrants (mh,nh):
//   P1: ds A-mh0(8) B-nh0(4); stage A-h0(T+1); bar; MFMA(mh0,nh0); bar
//   P2: ds B-nh1(4);          stage A-h1(T+1); bar; MFMA(mh0,nh1); bar
//   P3: ds A-mh1(8);          stage B-h0(T+2); bar; MFMA(mh1,nh0); bar
//   P4:                       stage B-h1(T+2); bar; MFMA(mh1,nh1); vmcnt; bar
// Safety: A(T+1)->buf[(T+1)&1] A-region last read (T-1).P3 (barrier between).
//         B(T+2)->buf[T&1] B-region last read T.P2 (barrier between).
// vmcnt LEDGER: steady state the 4 youngest in-flight loads at P4-end are
// B(T+2) -> vmcnt(4) leaves exactly those, guaranteeing tile T+1 landed.
// TAIL FIX (audit r3): at T=NT-2 no B(T+2) was issued, so the 4 youngest are
// A(NT-1) which tile NT-1 reads immediately -> must drain to vmcnt(0) there.
__global__ __launch_bounds__(512, 2) void qkv_gemm8(
    const unsigned short* __restrict__ xb, const unsigned short* __restrict__ wb,
    const float* __restrict__ bq, const float* __restrict__ bk, const float* __restrict__ bv,
    unsigned short* __restrict__ qb, unsigned short* __restrict__ kb, unsigned short* __restrict__ vb) {
  __shared__ unsigned short lds8[65536];      // 131072 B
  const int tid  = threadIdx.x;
  const int lane = tid & 63, wid = tid >> 6;
  const int wm = wid >> 2, wn = wid & 3;
  const int mt = blockIdx.x, nt = blockIdx.y;
  const int arow0 = mt * 256, brow0 = nt * 256;
  const int fr = lane & 15;
  const int fk16 = (lane >> 4) * 16;          // byte offset of k-chunk within 128B row
  // staging: thread covers LDS-linear 16B chunk; source col pre-swizzled
  const int srow = tid >> 3;                  // 0..63
  const int scol = (((tid & 7) * 16) ^ ((srow & 7) << 4)) >> 1;  // source elem col 0..63

  f32x4 acc[8][4];
#pragma unroll
  for (int i = 0; i < 8; ++i)
#pragma unroll
    for (int j = 0; j < 4; ++j) { f32x4 z = {0.f, 0.f, 0.f, 0.f}; acc[i][j] = z; }

  auto stageA = [&](int buf, int T, int h) {  // half h (128 rows) of A K-tile T
    unsigned short* d = lds8 + buf * 32768 + h * 8192 + tid * 8;
    const unsigned short* s = xb + (size_t)(arow0 + h * 128 + srow) * D_ + T * 64 + scol;
    gload16(s, d);
    gload16(s + (size_t)64 * D_, d + 4096);
  };
  auto stageB = [&](int buf, int T, int h) {
    unsigned short* d = lds8 + buf * 32768 + 16384 + h * 8192 + tid * 8;
    const unsigned short* s = wb + (size_t)(brow0 + h * 128 + srow) * D_ + T * 64 + scol;
    gload16(s, d);
    gload16(s + (size_t)64 * D_, d + 4096);
  };
  auto ldA = [&](int buf, int mh, int m2, int kk) -> bf16x8 {
    int row = wm * 128 + mh * 64 + m2 * 16 + fr;
    int cb = (kk * 64 + fk16) ^ ((row & 7) << 4);
    return *(const bf16x8*)(lds8 + buf * 32768 + row * 64 + (cb >> 1));
  };
  auto ldB = [&](int buf, int nh, int n2, int kk) -> bf16x8 {
    int row = wn * 64 + nh * 32 + n2 * 16 + fr;
    int cb = (kk * 64 + fk16) ^ ((row & 7) << 4);
    return *(const bf16x8*)(lds8 + buf * 32768 + 16384 + row * 64 + (cb >> 1));
  };

#define MFMA_QUAD(MH, NH, BFR)                                                     \
  do {                                                                             \
    __builtin_amdgcn_s_setprio(1);                                                 \
    _Pragma("unroll") for (int m2 = 0; m2 < 4; ++m2)                               \
    _Pragma("unroll") for (int n2 = 0; n2 < 2; ++n2)                               \
    _Pragma("unroll") for (int kk = 0; kk < 2; ++kk)                               \
      acc[(MH) * 4 + m2][(NH) * 2 + n2] = __builtin_amdgcn_mfma_f32_16x16x32_bf16( \
          afr[m2][kk], BFR[n2][kk], acc[(MH) * 4 + m2][(NH) * 2 + n2], 0, 0, 0);   \
    __builtin_amdgcn_s_setprio(0);                                                 \
  } while (0)

  constexpr int NT = 16;                      // K=1024 / 64
  // prologue: B(0), A(0), B(1) -> 12 loads; drain all but B(1) pair
  stageB(0, 0, 0); stageB(0, 0, 1);
  stageA(0, 0, 0); stageA(0, 0, 1);
  stageB(1, 1, 0); stageB(1, 1, 1);
  asm volatile("s_waitcnt vmcnt(4)" ::: "memory");
  __builtin_amdgcn_s_barrier();

  bf16x8 afr[4][2], bfr0[2][2], bfr1[2][2];
#pragma unroll 2
  for (int T = 0; T < NT; ++T) {
    const int cur = T & 1, nxt = cur ^ 1;
    // ---- P1 ----
#pragma unroll
    for (int n2 = 0; n2 < 2; ++n2)
#pragma unroll
      for (int kk = 0; kk < 2; ++kk) bfr0[n2][kk] = ldB(cur, 0, n2, kk);
#pragma unroll
    for (int m2 = 0; m2 < 4; ++m2)
#pragma unroll
      for (int kk = 0; kk < 2; ++kk) afr[m2][kk] = ldA(cur, 0, m2, kk);
    if (T + 1 < NT) stageA(nxt, T + 1, 0);
    __builtin_amdgcn_s_barrier();
    MFMA_QUAD(0, 0, bfr0);
    __builtin_amdgcn_s_barrier();
    // ---- P2 ----
#pragma unroll
    for (int n2 = 0; n2 < 2; ++n2)
#pragma unroll
      for (int kk = 0; kk < 2; ++kk) bfr1[n2][kk] = ldB(cur, 1, n2, kk);
    if (T + 1 < NT) stageA(nxt, T + 1, 1);
    __builtin_amdgcn_s_barrier();
    MFMA_QUAD(0, 1, bfr1);
    __builtin_amdgcn_s_barrier();
    // ---- P3 ----
#pragma unroll
    for (int m2 = 0; m2 < 4; ++m2)
#pragma unroll
      for (int kk = 0; kk < 2; ++kk) afr[m2][kk] = ldA(cur, 1, m2, kk);
    if (T + 2 < NT) stageB(cur, T + 2, 0);
    __builtin_amdgcn_s_barrier();
    MFMA_QUAD(1, 0, bfr0);
    __builtin_amdgcn_s_barrier();
    // ---- P4 ----
    if (T + 2 < NT) stageB(cur, T + 2, 1);
    __builtin_amdgcn_s_barrier();
    MFMA_QUAD(1, 1, bfr1);
    if (T + 2 < NT) {                         // steady state: 4 youngest = B(T+2)
      asm volatile("s_waitcnt vmcnt(4)" ::: "memory");
    } else {                                  // tail: youngest could be A(NT-1) -> drain
      asm volatile("s_waitcnt vmcnt(0)" ::: "memory");
    }
    __builtin_amdgcn_s_barrier();
  }
#undef MFMA_QUAD

  // epilogue: bias + bf16 store
  const int proj  = nt >> 2;                  // 4 tiles of 256 per projection
  const int ncol0 = (nt & 3) * 256;
  unsigned short* dst  = proj == 0 ? qb : (proj == 1 ? kb : vb);
  const float*    bias = proj == 0 ? bq : (proj == 1 ? bk : bv);
  const int dr = (lane >> 4) * 4, dc = lane & 15;
#pragma unroll
  for (int m = 0; m < 8; ++m)
#pragma unroll
    for (int n = 0; n < 4; ++n) {
      const int c = ncol0 + wn * 64 + n * 16 + dc;
      const float bb = bias[c];
#pragma unroll
      for (int q = 0; q < 4; ++q) {
        const int r = arow0 + wm * 128 + m * 16 + dr + q;
        dst[(size_t)r * D_ + c] = f2bf(acc[m][n][q] + bb);
      }
    }
}

// ---------------- shared 128x128 GEMM core (m97 structure) — scores/PV ----------------
DEV void gemm_tile(const unsigned short* __restrict__ A, int lda, int arow0,
                   const unsigned short* __restrict__ B, int ldb, int brow0,
                   int ksteps, unsigned short* lsA, unsigned short* lsB,
                   f32x4 acc[4][4]) {
  const int tid  = threadIdx.x;
  const int lane = tid & 63;
  const int w    = tid >> 6;
  const int wr   = (w >> 1) * 64, wc = (w & 1) * 64;
  const int srow = tid >> 3;
  const int scol = (tid & 7) * 8;
  const int fr   = lane & 15;
  const int fk   = (lane >> 4) * 8;

  for (int ks = 0; ks < ksteps; ++ks) {
    const int k0 = ks * 64;
#pragma unroll
    for (int p = 0; p < 4; ++p) {
      gload16(A + (size_t)(arow0 + p * 32 + srow) * lda + (k0 + scol), lsA + p * 2048 + tid * 8);
      gload16(B + (size_t)(brow0 + p * 32 + srow) * ldb + (k0 + scol), lsB + p * 2048 + tid * 8);
    }
    __syncthreads();
#pragma unroll
    for (int kk = 0; kk < 2; ++kk) {
      bf16x8 af[4], bfv[4];
#pragma unroll
      for (int i = 0; i < 4; ++i) {
        af[i]  = *(const bf16x8*)(lsA + (size_t)(wr + i * 16 + fr) * 64 + kk * 32 + fk);
        bfv[i] = *(const bf16x8*)(lsB + (size_t)(wc + i * 16 + fr) * 64 + kk * 32 + fk);
      }
#pragma unroll
      for (int i = 0; i < 4; ++i)
#pragma unroll
        for (int j = 0; j < 4; ++j)
          acc[i][j] = __builtin_amdgcn_mfma_f32_16x16x32_bf16(af[i], bfv[j], acc[i][j], 0, 0, 0);
    }
    __syncthreads();
  }
}

// ---------------- V transpose: [8192,1024] -> [1024,8192] ----------------
__global__ __launch_bounds__(256) void transpose_v(const unsigned short* __restrict__ vb,
                                                   unsigned short* __restrict__ vbT) {
  __shared__ unsigned short t[64][68];
  const int bt = blockIdx.x;
  const int bo = blockIdx.y;
  const int tid = threadIdx.x;
  const int r = tid >> 4, c4 = (tid & 15) * 4;
#pragma unroll
  for (int p = 0; p < 4; ++p) {
    ushort4 v = *(const ushort4*)(vb + (size_t)(bt * 64 + p * 16 + r) * D_ + bo * 64 + c4);
    t[p * 16 + r][c4] = v.x; t[p * 16 + r][c4 + 1] = v.y;
    t[p * 16 + r][c4 + 2] = v.z; t[p * 16 + r][c4 + 3] = v.w;
  }
  __syncthreads();
#pragma unroll
  for (int p = 0; p < 4; ++p) {
    ushort4 v;
    v.x = t[c4][p * 16 + r]; v.y = t[c4 + 1][p * 16 + r];
    v.z = t[c4 + 2][p * 16 + r]; v.w = t[c4 + 3][p * 16 + r];
    *(ushort4*)(vbT + (size_t)(bo * 64 + p * 16 + r) * NTOK + bt * 64 + c4) = v;
  }
}

// ---------------- scores = Q K^T * scale, causal lower-tri tiles only ----------------
__global__ __launch_bounds__(256) void scores_gemm(const unsigned short* __restrict__ qb,
                                                   const unsigned short* __restrict__ kb,
                                                   float* __restrict__ sbuf) {
  __shared__ unsigned short lsA[8192], lsB[8192];
  const int b = blockIdx.y;
  const int t = blockIdx.x;
  int i = (int)((sqrtf(8.f * t + 1.f) - 1.f) * 0.5f);
  while ((i + 1) * (i + 2) / 2 <= t) ++i;
  while (i * (i + 1) / 2 > t) --i;
  const int j = t - i * (i + 1) / 2;

  f32x4 acc[4][4];
#pragma unroll
  for (int a = 0; a < 4; ++a)
#pragma unroll
    for (int c = 0; c < 4; ++c) { f32x4 z = {0.f, 0.f, 0.f, 0.f}; acc[a][c] = z; }
  const unsigned short* Ab = qb + (size_t)b * S_ * D_;
  const unsigned short* Bb = kb + (size_t)b * S_ * D_;
  gemm_tile(Ab, D_, i * 128, Bb, D_, j * 128, 16, lsA, lsB, acc);

  float* sb = sbuf + (size_t)b * S_ * S_;
  const int lane = threadIdx.x & 63, w = threadIdx.x >> 6;
  const int wr = (w >> 1) * 64, wc = (w & 1) * 64;
  const int dr = (lane >> 4) * 4, dc = lane & 15;
  constexpr float scale = 0.03125f;
#pragma unroll
  for (int fi = 0; fi < 4; ++fi)
#pragma unroll
    for (int fj = 0; fj < 4; ++fj) {
      const int kv = j * 128 + wc + fj * 16 + dc;
#pragma unroll
      for (int q = 0; q < 4; ++q) {
        const int qr = i * 128 + wr + fi * 16 + dr + q;
        float v = acc[fi][fj][q] * scale;
        if (kv > qr) v = -1e30f;
        sb[(size_t)qr * S_ + kv] = v;
      }
    }
}

// ---------------- row softmax, P written bf16 in-place over scores ----------------
__global__ __launch_bounds__(256) void softmax_kernel(float* __restrict__ sbuf) {
  const int b = blockIdx.y, q = blockIdx.x;
  float* row = sbuf + ((size_t)b * S_ + q) * S_;
  unsigned short* prow = (unsigned short*)row;
  const int len = q + 1;
  __shared__ float buf[S_];
  __shared__ float red[4];
  const int tid = threadIdx.x, lane = tid & 63, wv = tid >> 6;

  float m = -3e38f;
  for (int k = tid; k < len; k += 256) { float s = row[k]; buf[k] = s; m = fmaxf(m, s); }
#pragma unroll
  for (int off = 32; off >= 1; off >>= 1) m = fmaxf(m, __shfl_xor(m, off));
  if (lane == 0) red[wv] = m;
  __syncthreads();
  m = fmaxf(fmaxf(red[0], red[1]), fmaxf(red[2], red[3]));
  __syncthreads();

  float l = 0.f;
  for (int k = tid; k < len; k += 256) { float e = __expf(buf[k] - m); buf[k] = e; l += e; }
#pragma unroll
  for (int off = 32; off >= 1; off >>= 1) l += __shfl_xor(l, off);
  if (lane == 0) red[wv] = l;
  __syncthreads();
  l = red[0] + red[1] + red[2] + red[3];
  const float inv = 1.f / l;
  for (int k = tid; k < S_; k += 256) {
    float p = (k < len) ? buf[k] * inv : 0.f;
    prow[k] = f2bf(p);
  }
}

// ---------------- O = P V  (causal K bound per row tile) ----------------
__global__ __launch_bounds__(256) void pv_gemm(const unsigned short* __restrict__ pbuf,
                                               const unsigned short* __restrict__ vbT,
                                               float* __restrict__ out) {
  __shared__ unsigned short lsA[8192], lsB[8192];
  const int it = 15 - blockIdx.x;       // longest blocks first
  const int nt = blockIdx.y;
  const int b  = blockIdx.z;
  f32x4 acc[4][4];
#pragma unroll
  for (int i = 0; i < 4; ++i)
#pragma unroll
    for (int j = 0; j < 4; ++j) { f32x4 z = {0.f, 0.f, 0.f, 0.f}; acc[i][j] = z; }
  const unsigned short* Ab = pbuf + (size_t)b * S_ * (2 * S_);
  const unsigned short* Bb = vbT + (size_t)b * S_;
  gemm_tile(Ab, 2 * S_, it * 128, Bb, NTOK, nt * 128, 2 * (it + 1), lsA, lsB, acc);

  const int lane = threadIdx.x & 63, w = threadIdx.x >> 6;
  const int wr = (w >> 1) * 64, wc = (w & 1) * 64;
  const int dr = (lane >> 4) * 4, dc = lane & 15;
#pragma unroll
  for (int fi = 0; fi < 4; ++fi)
#pragma unroll
    for (int fj = 0; fj < 4; ++fj) {
      const int c = nt * 128 + wc + fj * 16 + dc;
#pragma unroll
      for (int q = 0; q < 4; ++q) {
        const int r = it * 128 + wr + fi * 16 + dr + q;
        out[((size_t)b * S_ + r) * D_ + c] = acc[fi][fj][q];
      }
    }
}

extern "C" void kernel_launch(void* const* d_in, const int* in_sizes, int n_in,
                              void* d_out, int out_size, void* d_ws, size_t ws_size,
                              hipStream_t stream) {
  (void)in_sizes; (void)n_in; (void)out_size; (void)ws_size;
  const float* x  = (const float*)d_in[0];
  const float* wq = (const float*)d_in[1];
  const float* bq = (const float*)d_in[2];
  const float* wk = (const float*)d_in[3];
  const float* bk = (const float*)d_in[4];
  const float* wv = (const float*)d_in[5];
  const float* bv = (const float*)d_in[6];
  float* out = (float*)d_out;

  char* ws = (char*)d_ws;
  unsigned short* xb = (unsigned short*)(ws + OFF_XB);
  unsigned short* wb = (unsigned short*)(ws + OFF_WB);
  unsigned short* qb = (unsigned short*)(ws + OFF_QB);
  unsigned short* kb = (unsigned short*)(ws + OFF_KB);
  unsigned short* vb = (unsigned short*)(ws + OFF_VB);
  float*          sb = (float*)(ws + OFF_SB);
  unsigned short* vbT = xb;             // xb dead after qkv; reuse

  cast_kernel<<<2048, 256, 0, stream>>>(x,  xb, (int)(XB_ELEMS / 4));
  cast_kernel<<<1024, 256, 0, stream>>>(wq, wb,                 D_ * D_ / 4);
  cast_kernel<<<1024, 256, 0, stream>>>(wk, wb +     D_ * D_,   D_ * D_ / 4);
  cast_kernel<<<1024, 256, 0, stream>>>(wv, wb + 2 * D_ * D_,   D_ * D_ / 4);
  qkv_gemm8<<<dim3(32, 12), 512, 0, stream>>>(xb, wb, bq, bk, bv, qb, kb, vb);
  transpose_v<<<dim3(128, 16), 256, 0, stream>>>(vb, vbT);
  scores_gemm<<<dim3(136, 4), 256, 0, stream>>>(qb, kb, sb);
  softmax_kernel<<<dim3(S_, 4), 256, 0, stream>>>(sb);
  pv_gemm<<<dim3(16, 8, 4), 256, 0, stream>>>((const unsigned short*)sb, vbT, out);
}

// Round 6
// 274.160 us; speedup vs baseline: 1.0882x; 1.0250x over previous
//
#include <hip/hip_runtime.h>

#define DEV __device__ __forceinline__

typedef __bf16 bf16x8 __attribute__((ext_vector_type(8)));
typedef float  f32x4  __attribute__((ext_vector_type(4)));

// ---- constants ----
constexpr int B_ = 4, S_ = 2048, D_ = 1024;
constexpr int NTOK = B_ * S_;               // 8192
constexpr size_t XB_ELEMS = (size_t)NTOK * D_;        // 8,388,608
constexpr size_t WB_ELEMS = (size_t)3 * D_ * D_;      // 3,145,728
constexpr size_t OFF_XB = 0;
constexpr size_t OFF_WB = OFF_XB + XB_ELEMS * 2;      // 16,777,216
constexpr size_t OFF_QB = OFF_WB + WB_ELEMS * 2;      // 23,068,672
constexpr size_t OFF_KB = OFF_QB + XB_ELEMS * 2;
constexpr size_t OFF_VB = OFF_KB + XB_ELEMS * 2;
constexpr size_t OFF_SB = OFF_VB + XB_ELEMS * 2;      // 73,400,320 (fp32 scores, 67MB)
// P dense bf16 [B][S][S] = 33,554,432 B reuses qb+kb (dead after scores) at OFF_QB.

DEV unsigned short f2bf(float f) {            // RNE float->bf16
  unsigned u = __float_as_uint(f);
  u += 0x7fffu + ((u >> 16) & 1u);
  return (unsigned short)(u >> 16);
}

DEV void gload16(const void* g, void* l) {    // 16B global->LDS direct
  __builtin_amdgcn_global_load_lds(
      (const __attribute__((address_space(1))) void*)g,
      (__attribute__((address_space(3))) void*)l, 16, 0, 0);
}

// ---------------- fused cast fp32 -> bf16 (x, wq, wk, wv in one launch) ----------------
__global__ __launch_bounds__(256) void cast_all(const float* __restrict__ x,
                                                const float* __restrict__ wq,
                                                const float* __restrict__ wk,
                                                const float* __restrict__ wv,
                                                unsigned short* __restrict__ xb,
                                                unsigned short* __restrict__ wb) {
  constexpr int NX4 = (int)(XB_ELEMS / 4);    // 2,097,152
  constexpr int NW4 = D_ * D_ / 4;            // 262,144
  constexpr int NT4 = NX4 + 3 * NW4;
  int i = blockIdx.x * 256 + threadIdx.x;
  const int stride = gridDim.x * 256;
  for (; i < NT4; i += stride) {
    const float4* s;
    ushort4* d;
    if (i < NX4) {
      s = (const float4*)x + i;
      d = (ushort4*)xb + i;
    } else {
      int j = i - NX4;
      int seg = j / NW4;
      int off = j - seg * NW4;
      const float* w = seg == 0 ? wq : (seg == 1 ? wk : wv);
      s = (const float4*)w + off;
      d = (ushort4*)wb + (size_t)seg * NW4 + off;
    }
    float4 v = *s;
    ushort4 o;
    o.x = f2bf(v.x); o.y = f2bf(v.y); o.z = f2bf(v.z); o.w = f2bf(v.w);
    *d = o;
  }
}

// ================= 8-phase 256x128 GEMM (T2+T3+T4+T5), QKV =================
// Grid 32x24 = 768 blocks = exactly 3 full rounds on 256 CUs (tail-free).
// 512 thr = 8 waves (2M x 4N). Per wave: 128x32 out = acc[8][2]. BK=64.
// LDS per buf: A[256][64] (32KB) + B[128][64] (16KB); x2 bufs = 96KB.
// Swizzle: element (row,col) at col-byte (col*2)^((row&7)<<4); gload_lds writes
// linearly -> pre-swizzle the GLOBAL source col (both-sides involution).
// Phase schedule per K-tile T (buf = T&1), quadrants (mh, nh):
//   P1: ds afr-mh0(8) bfr0(2); stage A-h0(T+1)[2]; bar; MFMA(0,0)x8; bar
//   P2: ds bfr1(2);            stage A-h1(T+1)[2]; bar; MFMA(0,1)x8; bar
//   P3: ds afr-mh1(8);         stage B-h0(T+2)[1]; bar; MFMA(1,0)x8; bar
//   P4:                        stage B-h1(T+2)[1]; bar; MFMA(1,1)x8; vmcnt; bar
// LEDGER: end of tile T-1 leaves B(T+1)[2] outstanding. Tile T adds A(T+1)[4]
// + B(T+2)[2] = 8; vmcnt(2) retires the 6 oldest (B(T+1)+A(T+1)) -> tile T+1's
// operands resident; leaves B(T+2)[2]. Tail (T+2>=NT): no B issued -> vmcnt(0).
// Prologue: B(0)[2] A(0)[4] B(1)[2] -> vmcnt(2) retires B0+A0, leaves B1.
__global__ __launch_bounds__(512, 2) void qkv_gemm8(
    const unsigned short* __restrict__ xb, const unsigned short* __restrict__ wb,
    const float* __restrict__ bq, const float* __restrict__ bk, const float* __restrict__ bv,
    unsigned short* __restrict__ qb, unsigned short* __restrict__ kb, unsigned short* __restrict__ vb) {
  __shared__ unsigned short lds8[49152];      // 98,304 B
  const int tid  = threadIdx.x;
  const int lane = tid & 63, wid = tid >> 6;
  const int wm = wid >> 2, wn = wid & 3;
  const int mt = blockIdx.x, nt = blockIdx.y;
  const int arow0 = mt * 256, brow0 = nt * 128;
  const int fr = lane & 15;
  const int fk16 = (lane >> 4) * 16;          // byte offset of k-chunk within 128B row
  const int srow = tid >> 3;                  // 0..63
  const int scol = (((tid & 7) * 16) ^ ((srow & 7) << 4)) >> 1;  // pre-swizzled src col

  f32x4 acc[8][2];
#pragma unroll
  for (int i = 0; i < 8; ++i)
#pragma unroll
    for (int j = 0; j < 2; ++j) { f32x4 z = {0.f, 0.f, 0.f, 0.f}; acc[i][j] = z; }

  auto stageA = [&](int buf, int T, int h) {  // half h = 128 rows of A K-tile T (2 loads)
    unsigned short* d = lds8 + buf * 24576 + h * 8192 + tid * 8;
    const unsigned short* s = xb + (size_t)(arow0 + h * 128 + srow) * D_ + T * 64 + scol;
    gload16(s, d);
    gload16(s + (size_t)64 * D_, d + 4096);
  };
  auto stageB = [&](int buf, int T, int h) {  // half h = 64 rows of B K-tile T (1 load)
    unsigned short* d = lds8 + buf * 24576 + 16384 + h * 4096 + tid * 8;
    const unsigned short* s = wb + (size_t)(brow0 + h * 64 + srow) * D_ + T * 64 + scol;
    gload16(s, d);
  };
  auto ldA = [&](int buf, int mh, int m2, int kk) -> bf16x8 {
    int row = wm * 128 + mh * 64 + m2 * 16 + fr;
    int cb = (kk * 64 + fk16) ^ ((row & 7) << 4);
    return *(const bf16x8*)(lds8 + buf * 24576 + row * 64 + (cb >> 1));
  };
  auto ldB = [&](int buf, int nh, int kk) -> bf16x8 {
    int row = wn * 32 + nh * 16 + fr;
    int cb = (kk * 64 + fk16) ^ ((row & 7) << 4);
    return *(const bf16x8*)(lds8 + buf * 24576 + 16384 + row * 64 + (cb >> 1));
  };

#define MFMA_QUAD(MH, NH, BFR)                                                     \
  do {                                                                             \
    __builtin_amdgcn_s_setprio(1);                                                 \
    _Pragma("unroll") for (int m2 = 0; m2 < 4; ++m2)                               \
    _Pragma("unroll") for (int kk = 0; kk < 2; ++kk)                               \
      acc[(MH) * 4 + m2][(NH)] = __builtin_amdgcn_mfma_f32_16x16x32_bf16(          \
          afr[m2][kk], BFR[kk], acc[(MH) * 4 + m2][(NH)], 0, 0, 0);                \
    __builtin_amdgcn_s_setprio(0);                                                 \
  } while (0)

  constexpr int NT = 16;                      // K=1024 / 64
  stageB(0, 0, 0); stageB(0, 0, 1);
  stageA(0, 0, 0); stageA(0, 0, 1);
  stageB(1, 1, 0); stageB(1, 1, 1);
  asm volatile("s_waitcnt vmcnt(2)" ::: "memory");
  __builtin_amdgcn_s_barrier();

  bf16x8 afr[4][2], bfr0[2], bfr1[2];
#pragma unroll 2
  for (int T = 0; T < NT; ++T) {
    const int cur = T & 1, nxt = cur ^ 1;
    // ---- P1 ----
#pragma unroll
    for (int kk = 0; kk < 2; ++kk) bfr0[kk] = ldB(cur, 0, kk);
#pragma unroll
    for (int m2 = 0; m2 < 4; ++m2)
#pragma unroll
      for (int kk = 0; kk < 2; ++kk) afr[m2][kk] = ldA(cur, 0, m2, kk);
    if (T + 1 < NT) stageA(nxt, T + 1, 0);
    __builtin_amdgcn_s_barrier();
    MFMA_QUAD(0, 0, bfr0);
    __builtin_amdgcn_s_barrier();
    // ---- P2 ----
#pragma unroll
    for (int kk = 0; kk < 2; ++kk) bfr1[kk] = ldB(cur, 1, kk);
    if (T + 1 < NT) stageA(nxt, T + 1, 1);
    __builtin_amdgcn_s_barrier();
    MFMA_QUAD(0, 1, bfr1);
    __builtin_amdgcn_s_barrier();
    // ---- P3 ----
#pragma unroll
    for (int m2 = 0; m2 < 4; ++m2)
#pragma unroll
      for (int kk = 0; kk < 2; ++kk) afr[m2][kk] = ldA(cur, 1, m2, kk);
    if (T + 2 < NT) stageB(cur, T + 2, 0);
    __builtin_amdgcn_s_barrier();
    MFMA_QUAD(1, 0, bfr0);
    __builtin_amdgcn_s_barrier();
    // ---- P4 ----
    if (T + 2 < NT) stageB(cur, T + 2, 1);
    __builtin_amdgcn_s_barrier();
    MFMA_QUAD(1, 1, bfr1);
    if (T + 2 < NT) {
      asm volatile("s_waitcnt vmcnt(2)" ::: "memory");
    } else {
      asm volatile("s_waitcnt vmcnt(0)" ::: "memory");
    }
    __builtin_amdgcn_s_barrier();
  }
#undef MFMA_QUAD

  // epilogue: bias + bf16 store. nt in [0,24): proj = nt/8, col tile = nt%8.
  const int proj  = nt >> 3;
  const int ncol0 = (nt & 7) * 128;
  unsigned short* dst  = proj == 0 ? qb : (proj == 1 ? kb : vb);
  const float*    bias = proj == 0 ? bq : (proj == 1 ? bk : bv);
  const int dr = (lane >> 4) * 4, dc = lane & 15;
#pragma unroll
  for (int m = 0; m < 8; ++m)
#pragma unroll
    for (int n = 0; n < 2; ++n) {
      const int c = ncol0 + wn * 32 + n * 16 + dc;
      const float bb = bias[c];
#pragma unroll
      for (int q = 0; q < 4; ++q) {
        const int r = arow0 + wm * 128 + m * 16 + dr + q;
        dst[(size_t)r * D_ + c] = f2bf(acc[m][n][q] + bb);
      }
    }
}

// ---------------- shared 128x128 GEMM core (m97 structure) — scores/PV ----------------
DEV void gemm_tile(const unsigned short* __restrict__ A, int lda, int arow0,
                   const unsigned short* __restrict__ B, int ldb, int brow0,
                   int ksteps, unsigned short* lsA, unsigned short* lsB,
                   f32x4 acc[4][4]) {
  const int tid  = threadIdx.x;
  const int lane = tid & 63;
  const int w    = tid >> 6;
  const int wr   = (w >> 1) * 64, wc = (w & 1) * 64;
  const int srow = tid >> 3;
  const int scol = (tid & 7) * 8;
  const int fr   = lane & 15;
  const int fk   = (lane >> 4) * 8;

  for (int ks = 0; ks < ksteps; ++ks) {
    const int k0 = ks * 64;
#pragma unroll
    for (int p = 0; p < 4; ++p) {
      gload16(A + (size_t)(arow0 + p * 32 + srow) * lda + (k0 + scol), lsA + p * 2048 + tid * 8);
      gload16(B + (size_t)(brow0 + p * 32 + srow) * ldb + (k0 + scol), lsB + p * 2048 + tid * 8);
    }
    __syncthreads();
#pragma unroll
    for (int kk = 0; kk < 2; ++kk) {
      bf16x8 af[4], bfv[4];
#pragma unroll
      for (int i = 0; i < 4; ++i) {
        af[i]  = *(const bf16x8*)(lsA + (size_t)(wr + i * 16 + fr) * 64 + kk * 32 + fk);
        bfv[i] = *(const bf16x8*)(lsB + (size_t)(wc + i * 16 + fr) * 64 + kk * 32 + fk);
      }
#pragma unroll
      for (int i = 0; i < 4; ++i)
#pragma unroll
        for (int j = 0; j < 4; ++j)
          acc[i][j] = __builtin_amdgcn_mfma_f32_16x16x32_bf16(af[i], bfv[j], acc[i][j], 0, 0, 0);
    }
    __syncthreads();
  }
}

// ---------------- V transpose: [8192,1024] -> [1024,8192] ----------------
__global__ __launch_bounds__(256) void transpose_v(const unsigned short* __restrict__ vb,
                                                   unsigned short* __restrict__ vbT) {
  __shared__ unsigned short t[64][68];
  const int bt = blockIdx.x;
  const int bo = blockIdx.y;
  const int tid = threadIdx.x;
  const int r = tid >> 4, c4 = (tid & 15) * 4;
#pragma unroll
  for (int p = 0; p < 4; ++p) {
    ushort4 v = *(const ushort4*)(vb + (size_t)(bt * 64 + p * 16 + r) * D_ + bo * 64 + c4);
    t[p * 16 + r][c4] = v.x; t[p * 16 + r][c4 + 1] = v.y;
    t[p * 16 + r][c4 + 2] = v.z; t[p * 16 + r][c4 + 3] = v.w;
  }
  __syncthreads();
#pragma unroll
  for (int p = 0; p < 4; ++p) {
    ushort4 v;
    v.x = t[c4][p * 16 + r]; v.y = t[c4 + 1][p * 16 + r];
    v.z = t[c4 + 2][p * 16 + r]; v.w = t[c4 + 3][p * 16 + r];
    *(ushort4*)(vbT + (size_t)(bo * 64 + p * 16 + r) * NTOK + bt * 64 + c4) = v;
  }
}

// ---------------- scores = Q K^T * scale, causal lower-tri tiles only ----------------
__global__ __launch_bounds__(256) void scores_gemm(const unsigned short* __restrict__ qb,
                                                   const unsigned short* __restrict__ kb,
                                                   float* __restrict__ sbuf) {
  __shared__ unsigned short lsA[8192], lsB[8192];
  const int b = blockIdx.y;
  const int t = blockIdx.x;
  int i = (int)((sqrtf(8.f * t + 1.f) - 1.f) * 0.5f);
  while ((i + 1) * (i + 2) / 2 <= t) ++i;
  while (i * (i + 1) / 2 > t) --i;
  const int j = t - i * (i + 1) / 2;

  f32x4 acc[4][4];
#pragma unroll
  for (int a = 0; a < 4; ++a)
#pragma unroll
    for (int c = 0; c < 4; ++c) { f32x4 z = {0.f, 0.f, 0.f, 0.f}; acc[a][c] = z; }
  const unsigned short* Ab = qb + (size_t)b * S_ * D_;
  const unsigned short* Bb = kb + (size_t)b * S_ * D_;
  gemm_tile(Ab, D_, i * 128, Bb, D_, j * 128, 16, lsA, lsB, acc);

  float* sb = sbuf + (size_t)b * S_ * S_;
  const int lane = threadIdx.x & 63, w = threadIdx.x >> 6;
  const int wr = (w >> 1) * 64, wc = (w & 1) * 64;
  const int dr = (lane >> 4) * 4, dc = lane & 15;
  constexpr float scale = 0.03125f;
#pragma unroll
  for (int fi = 0; fi < 4; ++fi)
#pragma unroll
    for (int fj = 0; fj < 4; ++fj) {
      const int kv = j * 128 + wc + fj * 16 + dc;
#pragma unroll
      for (int q = 0; q < 4; ++q) {
        const int qr = i * 128 + wr + fi * 16 + dr + q;
        float v = acc[fi][fj][q] * scale;
        if (kv > qr) v = -1e30f;
        sb[(size_t)qr * S_ + kv] = v;
      }
    }
}

// ---------------- row softmax: fp32 scores -> dense bf16 P ----------------
// Writes P rows only to the causal 128-tile bound (pv reads exactly that much).
__global__ __launch_bounds__(256) void softmax_kernel(const float* __restrict__ sbuf,
                                                      unsigned short* __restrict__ pd) {
  const int b = blockIdx.y, q = blockIdx.x;
  const float* row = sbuf + ((size_t)b * S_ + q) * S_;
  unsigned short* prow = pd + ((size_t)b * S_ + q) * S_;
  const int len = q + 1;
  const int bound = (q & ~127) + 128;             // pv's k-extent for this row's tile
  __shared__ float buf[S_];
  __shared__ float red[4];
  const int tid = threadIdx.x, lane = tid & 63, wv = tid >> 6;

  float m = -3e38f;
  for (int k = tid; k < len; k += 256) { float s = row[k]; buf[k] = s; m = fmaxf(m, s); }
#pragma unroll
  for (int off = 32; off >= 1; off >>= 1) m = fmaxf(m, __shfl_xor(m, off));
  if (lane == 0) red[wv] = m;
  __syncthreads();
  m = fmaxf(fmaxf(red[0], red[1]), fmaxf(red[2], red[3]));
  __syncthreads();

  float l = 0.f;
  for (int k = tid; k < len; k += 256) { float e = __expf(buf[k] - m); buf[k] = e; l += e; }
#pragma unroll
  for (int off = 32; off >= 1; off >>= 1) l += __shfl_xor(l, off);
  if (lane == 0) red[wv] = l;
  __syncthreads();
  l = red[0] + red[1] + red[2] + red[3];
  const float inv = 1.f / l;
  for (int k = tid; k < bound; k += 256) {
    float p = (k < len) ? buf[k] * inv : 0.f;     // zero-fill to tile boundary for PV
    prow[k] = f2bf(p);
  }
}

// ---------------- O = P V  (causal K bound per row tile) ----------------
// Grid: x = q-row tile DESCENDING (longest blocks dispatch first), y = out-col tile, z = batch.
__global__ __launch_bounds__(256) void pv_gemm(const unsigned short* __restrict__ pd,
                                               const unsigned short* __restrict__ vbT,
                                               float* __restrict__ out) {
  __shared__ unsigned short lsA[8192], lsB[8192];
  const int it = 15 - blockIdx.x;       // longest blocks first
  const int nt = blockIdx.y;
  const int b  = blockIdx.z;
  f32x4 acc[4][4];
#pragma unroll
  for (int i = 0; i < 4; ++i)
#pragma unroll
    for (int j = 0; j < 4; ++j) { f32x4 z = {0.f, 0.f, 0.f, 0.f}; acc[i][j] = z; }
  const unsigned short* Ab = pd + (size_t)b * S_ * S_;         // dense P, lda = 2048
  const unsigned short* Bb = vbT + (size_t)b * S_;             // column offset into [1024,8192]
  gemm_tile(Ab, S_, it * 128, Bb, NTOK, nt * 128, 2 * (it + 1), lsA, lsB, acc);

  const int lane = threadIdx.x & 63, w = threadIdx.x >> 6;
  const int wr = (w >> 1) * 64, wc = (w & 1) * 64;
  const int dr = (lane >> 4) * 4, dc = lane & 15;
#pragma unroll
  for (int fi = 0; fi < 4; ++fi)
#pragma unroll
    for (int fj = 0; fj < 4; ++fj) {
      const int c = nt * 128 + wc + fj * 16 + dc;
#pragma unroll
      for (int q = 0; q < 4; ++q) {
        const int r = it * 128 + wr + fi * 16 + dr + q;
        out[((size_t)b * S_ + r) * D_ + c] = acc[fi][fj][q];
      }
    }
}

extern "C" void kernel_launch(void* const* d_in, const int* in_sizes, int n_in,
                              void* d_out, int out_size, void* d_ws, size_t ws_size,
                              hipStream_t stream) {
  (void)in_sizes; (void)n_in; (void)out_size; (void)ws_size;
  const float* x  = (const float*)d_in[0];
  const float* wq = (const float*)d_in[1];
  const float* bq = (const float*)d_in[2];
  const float* wk = (const float*)d_in[3];
  const float* bk = (const float*)d_in[4];
  const float* wv = (const float*)d_in[5];
  const float* bv = (const float*)d_in[6];
  float* out = (float*)d_out;

  char* ws = (char*)d_ws;
  unsigned short* xb = (unsigned short*)(ws + OFF_XB);
  unsigned short* wb = (unsigned short*)(ws + OFF_WB);
  unsigned short* qb = (unsigned short*)(ws + OFF_QB);
  unsigned short* kb = (unsigned short*)(ws + OFF_KB);
  unsigned short* vb = (unsigned short*)(ws + OFF_VB);
  float*          sb = (float*)(ws + OFF_SB);
  unsigned short* vbT = xb;             // xb dead after qkv; reuse (16.8MB)
  unsigned short* pd = qb;              // dense P [4][2048][2048] bf16 = 33.5MB over qb+kb
                                        // (both dead after scores_gemm)

  cast_all<<<2048, 256, 0, stream>>>(x, wq, wk, wv, xb, wb);
  qkv_gemm8<<<dim3(32, 24), 512, 0, stream>>>(xb, wb, bq, bk, bv, qb, kb, vb);
  transpose_v<<<dim3(128, 16), 256, 0, stream>>>(vb, vbT);
  scores_gemm<<<dim3(136, 4), 256, 0, stream>>>(qb, kb, sb);
  softmax_kernel<<<dim3(S_, 4), 256, 0, stream>>>(sb, pd);
  pv_gemm<<<dim3(16, 8, 4), 256, 0, stream>>>(pd, vbT, out);
}